// Round 1
// baseline (418.141 us; speedup 1.0000x reference)
//
#include <hip/hip_runtime.h>
#include <hip/hip_bf16.h>
#include <stdint.h>

// Problem constants
constexpr int CB  = 4;     // batch
constexpr int CS  = 2048;  // seq len
constexpr int CH  = 1024;  // hidden
constexpr int CNH = 16;    // heads
constexpr int CDH = 64;    // head dim
constexpr int CM  = CB * CS;  // 8192 rows

typedef __bf16 bf16x8 __attribute__((ext_vector_type(8)));
typedef float  f32x4  __attribute__((ext_vector_type(4)));

// round-to-nearest-even f32 -> bf16 (bit pattern)
__device__ __forceinline__ unsigned short f2bf(float f) {
    union { float f; unsigned u; } c; c.f = f;
    unsigned u = c.u;
    unsigned r = (u + 0x7fffu + ((u >> 16) & 1u)) >> 16;
    return (unsigned short)r;
}
__device__ __forceinline__ float bf2f(unsigned short h) {
    union { unsigned u; float f; } c; c.u = ((unsigned)h) << 16;
    return c.f;
}

// async global->LDS, 16B per lane. LDS dest = base + lane*16 (wave-uniform base).
__device__ __forceinline__ void gl_lds16(const void* g, void* l) {
    __builtin_amdgcn_global_load_lds((const __attribute__((address_space(1))) uint32_t*)g,
                                     (__attribute__((address_space(3))) uint32_t*)l,
                                     16, 0, 0);
}

// ---------------- fp32 -> bf16 convert (vectorized) ----------------
__global__ __launch_bounds__(256) void cvt_kernel(const float* __restrict__ src,
                                                  unsigned short* __restrict__ dst,
                                                  int n4) {
    int i = blockIdx.x * blockDim.x + threadIdx.x;
    if (i < n4) {
        float4 v = ((const float4*)src)[i];
        ushort4 o;
        o.x = f2bf(v.x); o.y = f2bf(v.y); o.z = f2bf(v.z); o.w = f2bf(v.w);
        ((ushort4*)dst)[i] = o;
    }
}

// ---------------- fused QKV projection GEMM ----------------
// C[m,n] = sum_k X[m,k] * W[n,k] + bias[n]   (nn.Linear: x @ W.T + b)
// z = 0(Q), 1(K): out [b,h,s,d];  z = 2(V): out transposed [b,h,d,s]
__global__ __launch_bounds__(256) void qkv_gemm(
    const unsigned short* __restrict__ Xb,   // [CM][CH] bf16
    const unsigned short* __restrict__ Wb,   // [3][CH][CH] bf16
    const float* __restrict__ bq, const float* __restrict__ bk, const float* __restrict__ bv,
    unsigned short* __restrict__ Qo,         // [CB*CNH, CS, CDH]
    unsigned short* __restrict__ Ko,
    unsigned short* __restrict__ Vt)         // [CB*CNH, CDH, CS]
{
    __shared__ alignas(16) unsigned short As[128][32];
    __shared__ alignas(16) unsigned short Bs[128][32];
    const int tid  = threadIdx.x;
    const int wave = tid >> 6, lane = tid & 63;
    const int wm = wave >> 1, wn = wave & 1;
    const int col = lane & 15, quad = lane >> 4;
    const int gm = blockIdx.x * 128, gn = blockIdx.y * 128;
    const int z  = blockIdx.z;
    const unsigned short* W = Wb + (size_t)z * CH * CH;

    f32x4 zero = {0.f, 0.f, 0.f, 0.f};
    f32x4 acc[4][4];
    for (int i = 0; i < 4; i++) for (int j = 0; j < 4; j++) acc[i][j] = zero;

    const int arow = lane >> 2;          // 0..15 (4 lanes per 64B row)
    const int acol = (lane & 3) * 8;     // 0,8,16,24

    for (int k0 = 0; k0 < CH; k0 += 32) {
        for (int c = 0; c < 2; ++c) {
            int r0 = wave * 32 + c * 16;
            gl_lds16(Xb + (size_t)(gm + r0 + arow) * CH + k0 + acol, &As[r0][0]);
            gl_lds16(W  + (size_t)(gn + r0 + arow) * CH + k0 + acol, &Bs[r0][0]);
        }
        __syncthreads();
        bf16x8 af[4], bfm[4];
        for (int i = 0; i < 4; i++)
            af[i] = *(const bf16x8*)&As[wm * 64 + i * 16 + col][quad * 8];
        for (int j = 0; j < 4; j++)
            bfm[j] = *(const bf16x8*)&Bs[wn * 64 + j * 16 + col][quad * 8];
        for (int i = 0; i < 4; i++)
            for (int j = 0; j < 4; j++)
                acc[i][j] = __builtin_amdgcn_mfma_f32_16x16x32_bf16(af[i], bfm[j], acc[i][j], 0, 0, 0);
        __syncthreads();
    }

    const float* bias = (z == 0) ? bq : (z == 1) ? bk : bv;
    unsigned short* dst01 = (z == 0) ? Qo : Ko;
    for (int j = 0; j < 4; j++) {
        int n = gn + wn * 64 + j * 16 + col;
        float bias_v = bias[n];
        int h = n >> 6, d = n & 63;
        for (int i = 0; i < 4; i++) {
            for (int r = 0; r < 4; r++) {
                int m = gm + wm * 64 + i * 16 + quad * 4 + r;
                float v = acc[i][j][r] + bias_v;
                int bb = m >> 11, ss = m & 2047;
                if (z == 2)
                    Vt[((size_t)(bb * CNH + h) * CDH + d) * CS + ss] = f2bf(v);
                else
                    dst01[((size_t)(bb * CNH + h) * CS + ss) * CDH + d] = f2bf(v);
            }
        }
    }
}

// ---------------- flash attention ----------------
// grid: (CS/256, CB*CNH); block 256. Each wave owns 64 q rows.
__global__ __launch_bounds__(256, 2) void flash_attn(
    const unsigned short* __restrict__ Q,    // [CB*CNH, CS, CDH]
    const unsigned short* __restrict__ K,
    const unsigned short* __restrict__ Vt,   // [CB*CNH, CDH, CS]
    const int* __restrict__ mask,            // [CB, CS]
    float* __restrict__ out)                 // [CB, CS, CH]
{
    __shared__ alignas(16) unsigned short Ks[64][64];
    __shared__ alignas(16) unsigned short Vs[64][64];   // [d][kv]
    __shared__ alignas(16) unsigned short Ps[4][64][64];
    const int tid  = threadIdx.x;
    const int wave = tid >> 6, lane = tid & 63;
    const int col = lane & 15, quad = lane >> 4;
    const int bh = blockIdx.y;
    const int bI = bh >> 4, hI = bh & 15;
    const int q0 = blockIdx.x * 256 + wave * 64;

    const unsigned short* Qp = Q  + (size_t)bh * CS * CDH;
    const unsigned short* Kp = K  + (size_t)bh * CS * CDH;
    const unsigned short* Vp = Vt + (size_t)bh * CDH * CS;

    // Q fragments held in registers: A[m=lane&15][k=quad*8+j]
    bf16x8 aq[4][2];
    for (int i = 0; i < 4; i++)
        for (int ks = 0; ks < 2; ks++)
            aq[i][ks] = *(const bf16x8*)(Qp + (size_t)(q0 + i * 16 + col) * CDH + ks * 32 + quad * 8);

    f32x4 zero = {0.f, 0.f, 0.f, 0.f};
    f32x4 o[4][4];
    float mrow[4][4], lrow[4][4];
    for (int i = 0; i < 4; i++)
        for (int j = 0; j < 4; j++) o[i][j] = zero;
    for (int i = 0; i < 4; i++)
        for (int r = 0; r < 4; r++) { mrow[i][r] = -3.0e38f; lrow[i][r] = 0.f; }

    const int srow = lane >> 3;          // 0..7 (8 lanes per 128B row)
    const int scol = (lane & 7) * 8;

    for (int kt = 0; kt < 32; ++kt) {
        __syncthreads();   // protect LDS tiles from previous iteration's readers
        {   // K tile: contiguous 8KB
            const unsigned short* kg = Kp + (size_t)kt * 64 * CDH;
            for (int c = 0; c < 2; c++) {
                int chunk0 = wave * 128 + c * 64;
                gl_lds16(kg + (size_t)(chunk0 + lane) * 8, &Ks[0][0] + (size_t)chunk0 * 8);
            }
            // V^T tile: rows are d (stride CS in global)
            for (int c = 0; c < 2; c++) {
                int r0 = wave * 16 + c * 8;
                gl_lds16(Vp + (size_t)(r0 + srow) * CS + kt * 64 + scol, &Vs[r0][0]);
            }
        }
        __syncthreads();

        float madd[4];
        for (int ik = 0; ik < 4; ik++) {
            int kv = kt * 64 + ik * 16 + col;
            madd[ik] = mask[bI * CS + kv] ? 0.f : -1.0e30f;
        }

        // S = Q K^T  (64 q x 64 kv), fp32 acc
        f32x4 sfr[4][4];
        for (int i = 0; i < 4; i++) for (int ik = 0; ik < 4; ik++) sfr[i][ik] = zero;
        for (int ks = 0; ks < 2; ks++) {
            bf16x8 bk_[4];
            for (int ik = 0; ik < 4; ik++)
                bk_[ik] = *(const bf16x8*)&Ks[ik * 16 + col][ks * 32 + quad * 8];
            for (int i = 0; i < 4; i++)
                for (int ik = 0; ik < 4; ik++)
                    sfr[i][ik] = __builtin_amdgcn_mfma_f32_16x16x32_bf16(aq[i][ks], bk_[ik], sfr[i][ik], 0, 0, 0);
        }

        // scale + mask
        for (int i = 0; i < 4; i++)
            for (int ik = 0; ik < 4; ik++)
                for (int r = 0; r < 4; r++)
                    sfr[i][ik][r] = sfr[i][ik][r] * 0.125f + madd[ik];

        // row max (4 frags, then 16-lane butterfly within quad)
        float rm[4][4];
        for (int i = 0; i < 4; i++)
            for (int r = 0; r < 4; r++)
                rm[i][r] = fmaxf(fmaxf(sfr[i][0][r], sfr[i][1][r]), fmaxf(sfr[i][2][r], sfr[i][3][r]));
        for (int off = 1; off < 16; off <<= 1)
            for (int i = 0; i < 4; i++)
                for (int r = 0; r < 4; r++)
                    rm[i][r] = fmaxf(rm[i][r], __shfl_xor(rm[i][r], off, 64));

        // online rescale: m_new, alpha applied to l and O immediately
        for (int i = 0; i < 4; i++)
            for (int r = 0; r < 4; r++) {
                float mn = fmaxf(mrow[i][r], rm[i][r]);
                float alpha = __expf(mrow[i][r] - mn);
                mrow[i][r] = mn;
                lrow[i][r] *= alpha;
                for (int id = 0; id < 4; id++) o[i][id][r] *= alpha;
            }

        // P = exp(s - m), bf16-rounded; rowsum of rounded P; write to per-wave LDS
        float rs[4][4];
        for (int i = 0; i < 4; i++) for (int r = 0; r < 4; r++) rs[i][r] = 0.f;
        for (int i = 0; i < 4; i++)
            for (int ik = 0; ik < 4; ik++)
                for (int r = 0; r < 4; r++) {
                    float p = __expf(sfr[i][ik][r] - mrow[i][r]);
                    unsigned short pb = f2bf(p);
                    rs[i][r] += bf2f(pb);
                    Ps[wave][i * 16 + quad * 4 + r][ik * 16 + col] = pb;
                }
        for (int off = 1; off < 16; off <<= 1)
            for (int i = 0; i < 4; i++)
                for (int r = 0; r < 4; r++)
                    rs[i][r] += __shfl_xor(rs[i][r], off, 64);
        for (int i = 0; i < 4; i++)
            for (int r = 0; r < 4; r++)
                lrow[i][r] += rs[i][r];

        // O += P V   (A = P [q][kv] from LDS, B[k=kv][n=d] = Vs[d][kv])
        for (int ks = 0; ks < 2; ks++) {
            bf16x8 ap[4], bv_[4];
            for (int i = 0; i < 4; i++)
                ap[i] = *(const bf16x8*)&Ps[wave][i * 16 + col][ks * 32 + quad * 8];
            for (int id = 0; id < 4; id++)
                bv_[id] = *(const bf16x8*)&Vs[id * 16 + col][ks * 32 + quad * 8];
            for (int i = 0; i < 4; i++)
                for (int id = 0; id < 4; id++)
                    o[i][id] = __builtin_amdgcn_mfma_f32_16x16x32_bf16(ap[i], bv_[id], o[i][id], 0, 0, 0);
        }
    }

    // epilogue: out[b][s][h*64+d] = O / l
    for (int i = 0; i < 4; i++)
        for (int r = 0; r < 4; r++) {
            int sI = q0 + i * 16 + quad * 4 + r;
            float inv = 1.0f / lrow[i][r];
            for (int id = 0; id < 4; id++) {
                int d = id * 16 + col;
                out[((size_t)(bI * CS + sI)) * CH + hI * CDH + d] = o[i][id][r] * inv;
            }
        }
}

extern "C" void kernel_launch(void* const* d_in, const int* in_sizes, int n_in,
                              void* d_out, int out_size, void* d_ws, size_t ws_size,
                              hipStream_t stream) {
    const float* hs  = (const float*)d_in[0];
    const int*  mask = (const int*)d_in[1];
    const float* Wq  = (const float*)d_in[2];
    const float* bq  = (const float*)d_in[3];
    const float* Wk  = (const float*)d_in[4];
    const float* bk  = (const float*)d_in[5];
    const float* Wv  = (const float*)d_in[6];
    const float* bv  = (const float*)d_in[7];
    float* out = (float*)d_out;

    char* ws = (char*)d_ws;
    unsigned short* Xb = (unsigned short*)(ws);                    // 16 MB
    unsigned short* Wb = (unsigned short*)(ws + 16777216);         // 6 MB (3x H*H)
    unsigned short* Qb = (unsigned short*)(ws + 23068672);         // 16 MB
    unsigned short* Kb = (unsigned short*)(ws + 39845888);         // 16 MB
    unsigned short* Vt = (unsigned short*)(ws + 56623104);         // 16 MB

    // fp32 -> bf16
    cvt_kernel<<<dim3((CM * CH / 4 + 255) / 256), 256, 0, stream>>>(hs, Xb, CM * CH / 4);
    cvt_kernel<<<dim3((CH * CH / 4 + 255) / 256), 256, 0, stream>>>(Wq, Wb + 0 * CH * CH, CH * CH / 4);
    cvt_kernel<<<dim3((CH * CH / 4 + 255) / 256), 256, 0, stream>>>(Wk, Wb + 1 * CH * CH, CH * CH / 4);
    cvt_kernel<<<dim3((CH * CH / 4 + 255) / 256), 256, 0, stream>>>(Wv, Wb + 2 * CH * CH, CH * CH / 4);

    // fused QKV projections
    qkv_gemm<<<dim3(CM / 128, CH / 128, 3), 256, 0, stream>>>(Xb, Wb, bq, bk, bv, Qb, Kb, Vt);

    // flash attention
    flash_attn<<<dim3(CS / 256, CB * CNH), 256, 0, stream>>>(Qb, Kb, Vt, mask, out);
}

// Round 2
// 332.521 us; speedup vs baseline: 1.2575x; 1.2575x over previous
//
#include <hip/hip_runtime.h>
#include <hip/hip_bf16.h>
#include <stdint.h>

// Problem constants
constexpr int CB  = 4;     // batch
constexpr int CS  = 2048;  // seq len
constexpr int CH  = 1024;  // hidden
constexpr int CNH = 16;    // heads
constexpr int CDH = 64;    // head dim
constexpr int CM  = CB * CS;  // 8192 rows

typedef __bf16 bf16x8 __attribute__((ext_vector_type(8)));
typedef float  f32x4  __attribute__((ext_vector_type(4)));

// round-to-nearest-even f32 -> bf16 (bit pattern)
__device__ __forceinline__ unsigned short f2bf(float f) {
    union { float f; unsigned u; } c; c.f = f;
    unsigned u = c.u;
    unsigned r = (u + 0x7fffu + ((u >> 16) & 1u)) >> 16;
    return (unsigned short)r;
}

// async global->LDS, 16B per lane. LDS dest = base + lane*16 (wave-uniform base).
__device__ __forceinline__ void gl_lds16(const void* g, void* l) {
    __builtin_amdgcn_global_load_lds((const __attribute__((address_space(1))) uint32_t*)g,
                                     (__attribute__((address_space(3))) uint32_t*)l,
                                     16, 0, 0);
}

__device__ __forceinline__ float fexp2(float x) {
#if __has_builtin(__builtin_amdgcn_exp2f)
    return __builtin_amdgcn_exp2f(x);
#else
    return exp2f(x);
#endif
}

// max across each 16-lane DPP row via row_ror 1,2,4,8 (VALU pipe, no LDS)
__device__ __forceinline__ float rowmax16(float x) {
    union { float f; int i; } c, d;
    c.f = x; d.i = __builtin_amdgcn_update_dpp(0, c.i, 0x121, 0xf, 0xf, true); x = fmaxf(x, d.f);
    c.f = x; d.i = __builtin_amdgcn_update_dpp(0, c.i, 0x122, 0xf, 0xf, true); x = fmaxf(x, d.f);
    c.f = x; d.i = __builtin_amdgcn_update_dpp(0, c.i, 0x124, 0xf, 0xf, true); x = fmaxf(x, d.f);
    c.f = x; d.i = __builtin_amdgcn_update_dpp(0, c.i, 0x128, 0xf, 0xf, true); x = fmaxf(x, d.f);
    return x;
}

// ---------------- fp32 -> bf16 converts ----------------
__global__ __launch_bounds__(256) void cvt_kernel(const float* __restrict__ src,
                                                  unsigned short* __restrict__ dst,
                                                  int n4) {
    int i = blockIdx.x * blockDim.x + threadIdx.x;
    if (i < n4) {
        float4 v = ((const float4*)src)[i];
        ushort4 o;
        o.x = f2bf(v.x); o.y = f2bf(v.y); o.z = f2bf(v.z); o.w = f2bf(v.w);
        ((ushort4*)dst)[i] = o;
    }
}

__global__ __launch_bounds__(256) void cvt3_kernel(const float* __restrict__ s0,
                                                   const float* __restrict__ s1,
                                                   const float* __restrict__ s2,
                                                   unsigned short* __restrict__ dst,
                                                   int n4each) {
    int z = blockIdx.y;
    const float* src = (z == 0) ? s0 : (z == 1) ? s1 : s2;
    int i = blockIdx.x * blockDim.x + threadIdx.x;
    if (i < n4each) {
        float4 v = ((const float4*)src)[i];
        ushort4 o;
        o.x = f2bf(v.x); o.y = f2bf(v.y); o.z = f2bf(v.z); o.w = f2bf(v.w);
        ((ushort4*)(dst + (size_t)z * n4each * 4))[i] = o;
    }
}

// ---------------- fused QKV projection GEMM (unchanged) ----------------
__global__ __launch_bounds__(256) void qkv_gemm(
    const unsigned short* __restrict__ Xb,
    const unsigned short* __restrict__ Wb,
    const float* __restrict__ bq, const float* __restrict__ bk, const float* __restrict__ bv,
    unsigned short* __restrict__ Qo,
    unsigned short* __restrict__ Ko,
    unsigned short* __restrict__ Vt)
{
    __shared__ alignas(16) unsigned short As[128][32];
    __shared__ alignas(16) unsigned short Bs[128][32];
    const int tid  = threadIdx.x;
    const int wave = tid >> 6, lane = tid & 63;
    const int wm = wave >> 1, wn = wave & 1;
    const int col = lane & 15, quad = lane >> 4;
    const int gm = blockIdx.x * 128, gn = blockIdx.y * 128;
    const int z  = blockIdx.z;
    const unsigned short* W = Wb + (size_t)z * CH * CH;

    f32x4 zero = {0.f, 0.f, 0.f, 0.f};
    f32x4 acc[4][4];
    for (int i = 0; i < 4; i++) for (int j = 0; j < 4; j++) acc[i][j] = zero;

    const int arow = lane >> 2;
    const int acol = (lane & 3) * 8;

    for (int k0 = 0; k0 < CH; k0 += 32) {
        for (int c = 0; c < 2; ++c) {
            int r0 = wave * 32 + c * 16;
            gl_lds16(Xb + (size_t)(gm + r0 + arow) * CH + k0 + acol, &As[r0][0]);
            gl_lds16(W  + (size_t)(gn + r0 + arow) * CH + k0 + acol, &Bs[r0][0]);
        }
        __syncthreads();
        bf16x8 af[4], bfm[4];
        for (int i = 0; i < 4; i++)
            af[i] = *(const bf16x8*)&As[wm * 64 + i * 16 + col][quad * 8];
        for (int j = 0; j < 4; j++)
            bfm[j] = *(const bf16x8*)&Bs[wn * 64 + j * 16 + col][quad * 8];
        for (int i = 0; i < 4; i++)
            for (int j = 0; j < 4; j++)
                acc[i][j] = __builtin_amdgcn_mfma_f32_16x16x32_bf16(af[i], bfm[j], acc[i][j], 0, 0, 0);
        __syncthreads();
    }

    const float* bias = (z == 0) ? bq : (z == 1) ? bk : bv;
    unsigned short* dst01 = (z == 0) ? Qo : Ko;
    for (int j = 0; j < 4; j++) {
        int n = gn + wn * 64 + j * 16 + col;
        float bias_v = bias[n];
        int h = n >> 6, d = n & 63;
        for (int i = 0; i < 4; i++) {
            for (int r = 0; r < 4; r++) {
                int m = gm + wm * 64 + i * 16 + quad * 4 + r;
                float v = acc[i][j][r] + bias_v;
                int bb = m >> 11, ss = m & 2047;
                if (z == 2)
                    Vt[((size_t)(bb * CNH + h) * CDH + d) * CS + ss] = f2bf(v);
                else
                    dst01[((size_t)(bb * CNH + h) * CS + ss) * CDH + d] = f2bf(v);
            }
        }
    }
}

// ---------------- flash attention v2 ----------------
// grid: (CS/128, CB*CNH); block 256. Each wave owns 32 q rows.
// LDS tiles XOR-swizzled in 16B chunks: chunk' = chunk ^ (row & 7).
__global__ __launch_bounds__(256, 4) void flash_attn(
    const unsigned short* __restrict__ Q,    // [B*h, S, d]
    const unsigned short* __restrict__ K,    // [B*h, S, d]
    const unsigned short* __restrict__ Vt,   // [B*h, d, S]
    const int* __restrict__ mask,            // [B, S]
    float* __restrict__ out)                 // [B, S, H]
{
    __shared__ alignas(16) unsigned short Ks[64][64];
    __shared__ alignas(16) unsigned short Vs[64][64];   // [d][kv]
    __shared__ alignas(16) unsigned short Ps[4][32][64];
    __shared__ unsigned int Mbits[64];                  // 2048-bit mask

    const int tid  = threadIdx.x;
    const int wave = tid >> 6, lane = tid & 63;
    const int col = lane & 15, quad = lane >> 4;
    const int bh = blockIdx.y;
    const int bI = bh >> 4, hI = bh & 15;
    const int q0 = blockIdx.x * 128 + wave * 32;

    const unsigned short* Qp = Q  + (size_t)bh * CS * CDH;
    const unsigned short* Kp = K  + (size_t)bh * CS * CDH;
    const unsigned short* Vp = Vt + (size_t)bh * CDH * CS;

    // mask -> bitmask in LDS (one ballot per 64 kv)
    {
        const int* mg = mask + bI * CS;
        for (int j = 0; j < 8; j++) {
            int idx = wave * 512 + j * 64 + lane;
            unsigned long long bal = __ballot(mg[idx] != 0);
            if (lane == 0) {
                Mbits[wave * 16 + j * 2]     = (unsigned int)bal;
                Mbits[wave * 16 + j * 2 + 1] = (unsigned int)(bal >> 32);
            }
        }
    }

    // Q fragments in registers: A[m=col][k=quad*8+j]
    bf16x8 aq[2][2];
    for (int i = 0; i < 2; i++)
        for (int ks = 0; ks < 2; ks++)
            aq[i][ks] = *(const bf16x8*)(Qp + (size_t)(q0 + i * 16 + col) * CDH + ks * 32 + quad * 8);

    bf16x8 onesb;
    {
        union { unsigned short u; __bf16 b; } ob; ob.u = 0x3F80;  // bf16 1.0
        for (int j = 0; j < 8; j++) onesb[j] = ob.b;
    }

    f32x4 zero = {0.f, 0.f, 0.f, 0.f};
    f32x4 o[2][4], lfr[2];
    float mrow[2][4];
    for (int i = 0; i < 2; i++) {
        lfr[i] = zero;
        for (int id = 0; id < 4; id++) o[i][id] = zero;
        for (int r = 0; r < 4; r++) mrow[i][r] = -1.0e38f;
    }

    const int srow = lane >> 3;              // row within 8-row staging group
    const int schk = (lane & 7) ^ srow;      // swizzled global chunk index
    const float SC = 0.125f * 1.44269504f;   // 1/sqrt(dh) * log2(e)

    for (int kt = 0; kt < 32; ++kt) {
        __syncthreads();
        {
            const unsigned short* kg = Kp + (size_t)kt * 64 * CDH;
            for (int c = 0; c < 2; c++) {
                int r0 = wave * 16 + c * 8;
                gl_lds16(kg + (size_t)(r0 + srow) * CDH + schk * 8, &Ks[r0][0]);
                gl_lds16(Vp + (size_t)(r0 + srow) * CS + kt * 64 + schk * 8, &Vs[r0][0]);
            }
        }
        __syncthreads();

        unsigned int w0 = Mbits[kt * 2], w1 = Mbits[kt * 2 + 1];
        float madd[4];
        madd[0] = ((w0 >> col) & 1u)        ? 0.f : -1.0e30f;
        madd[1] = ((w0 >> (col + 16)) & 1u) ? 0.f : -1.0e30f;
        madd[2] = ((w1 >> col) & 1u)        ? 0.f : -1.0e30f;
        madd[3] = ((w1 >> (col + 16)) & 1u) ? 0.f : -1.0e30f;

        // S' = QK^T * SC + madd   (base-2 softmax domain)
        f32x4 sfr[2][4];
        for (int i = 0; i < 2; i++) for (int ik = 0; ik < 4; ik++) sfr[i][ik] = zero;
        for (int ks = 0; ks < 2; ks++) {
            bf16x8 bkf[4];
            for (int ik = 0; ik < 4; ik++)
                bkf[ik] = *(const bf16x8*)&Ks[ik * 16 + col][((ks * 4 + quad) ^ (col & 7)) * 8];
            for (int i = 0; i < 2; i++)
                for (int ik = 0; ik < 4; ik++)
                    sfr[i][ik] = __builtin_amdgcn_mfma_f32_16x16x32_bf16(aq[i][ks], bkf[ik], sfr[i][ik], 0, 0, 0);
        }
        for (int i = 0; i < 2; i++)
            for (int ik = 0; ik < 4; ik++)
                for (int r = 0; r < 4; r++)
                    sfr[i][ik][r] = sfr[i][ik][r] * SC + madd[ik];

        // row max: in-register across ik, then DPP across the 16-lane row
        float rm[2][4];
        for (int i = 0; i < 2; i++)
            for (int r = 0; r < 4; r++) {
                float v = fmaxf(fmaxf(sfr[i][0][r], sfr[i][1][r]), fmaxf(sfr[i][2][r], sfr[i][3][r]));
                rm[i][r] = rowmax16(v);
            }

        // online rescale (O and l share alpha; l is MFMA-accumulated below)
        for (int i = 0; i < 2; i++)
            for (int r = 0; r < 4; r++) {
                float mn = fmaxf(mrow[i][r], rm[i][r]);
                float al = fexp2(mrow[i][r] - mn);
                mrow[i][r] = mn;
                lfr[i][r] *= al;
                for (int id = 0; id < 4; id++) o[i][id][r] *= al;
            }

        // P = 2^(s'-m), truncate to bf16, store swizzled (scalar b16 writes)
        for (int i = 0; i < 2; i++)
            for (int ik = 0; ik < 4; ik++)
                for (int r = 0; r < 4; r++) {
                    float p = fexp2(sfr[i][ik][r] - mrow[i][r]);
                    union { float f; unsigned u; } cu; cu.f = p;
                    int row = i * 16 + quad * 4 + r;
                    int slot = (ik * 2 + (col >> 3)) ^ (row & 7);
                    Ps[wave][row][slot * 8 + (col & 7)] = (unsigned short)(cu.u >> 16);
                }

        // O += P V ; l += P·1 (ones-column MFMA keeps l consistent with rounded P)
        for (int ks = 0; ks < 2; ks++) {
            bf16x8 ap[2], bvf[4];
            for (int i = 0; i < 2; i++)
                ap[i] = *(const bf16x8*)&Ps[wave][i * 16 + col][((ks * 4 + quad) ^ (col & 7)) * 8];
            for (int id = 0; id < 4; id++)
                bvf[id] = *(const bf16x8*)&Vs[id * 16 + col][((ks * 4 + quad) ^ (col & 7)) * 8];
            for (int i = 0; i < 2; i++) {
                for (int id = 0; id < 4; id++)
                    o[i][id] = __builtin_amdgcn_mfma_f32_16x16x32_bf16(ap[i], bvf[id], o[i][id], 0, 0, 0);
                lfr[i] = __builtin_amdgcn_mfma_f32_16x16x32_bf16(ap[i], onesb, lfr[i], 0, 0, 0);
            }
        }
    }

    // epilogue: out[b][s][h*64+d] = O / l
    for (int i = 0; i < 2; i++)
        for (int r = 0; r < 4; r++) {
            int sI = q0 + i * 16 + quad * 4 + r;
            float inv = 1.0f / lfr[i][r];
            for (int id = 0; id < 4; id++)
                out[((size_t)(bI * CS + sI)) * CH + hI * CDH + id * 16 + col] = o[i][id][r] * inv;
        }
}

extern "C" void kernel_launch(void* const* d_in, const int* in_sizes, int n_in,
                              void* d_out, int out_size, void* d_ws, size_t ws_size,
                              hipStream_t stream) {
    const float* hs  = (const float*)d_in[0];
    const int*  mask = (const int*)d_in[1];
    const float* Wq  = (const float*)d_in[2];
    const float* bq  = (const float*)d_in[3];
    const float* Wk  = (const float*)d_in[4];
    const float* bk  = (const float*)d_in[5];
    const float* Wv  = (const float*)d_in[6];
    const float* bv  = (const float*)d_in[7];
    float* out = (float*)d_out;

    char* ws = (char*)d_ws;
    unsigned short* Xb = (unsigned short*)(ws);                    // 16 MB
    unsigned short* Wb = (unsigned short*)(ws + 16777216);         // 6 MB
    unsigned short* Qb = (unsigned short*)(ws + 23068672);         // 16 MB
    unsigned short* Kb = (unsigned short*)(ws + 39845888);         // 16 MB
    unsigned short* Vt = (unsigned short*)(ws + 56623104);         // 16 MB

    cvt_kernel<<<dim3((CM * CH / 4 + 255) / 256), 256, 0, stream>>>(hs, Xb, CM * CH / 4);
    cvt3_kernel<<<dim3((CH * CH / 4 + 255) / 256, 3), 256, 0, stream>>>(Wq, Wk, Wv, Wb, CH * CH / 4);

    qkv_gemm<<<dim3(CM / 128, CH / 128, 3), 256, 0, stream>>>(Xb, Wb, bq, bk, bv, Qb, Kb, Vt);

    flash_attn<<<dim3(CS / 128, CB * CNH), 256, 0, stream>>>(Qb, Kb, Vt, mask, out);
}